// Round 4
// baseline (5924.046 us; speedup 1.0000x reference)
//
#include <hip/hip_runtime.h>
#include <hip/hip_bf16.h>
#include <hip/hip_fp16.h>

// SARDecoder: 31-step teacher-forced attention LSTM decoder. fp32 in/out.
// Round 4: persistent multi-step kernel with grid barriers + transposed bf16 weights.
// B=32, RNN=ATT=FEAT=512, V1=111, H=8, W=32, STEPS=31, P=256.

#define RNN   512
#define V1    111
#define STEPS 31
#define HWP   256
#define NB    128     // persistent-kernel blocks (co-resident: <= 256 CUs)

typedef unsigned short ushortT;
typedef unsigned int   uintT;

__device__ __forceinline__ float blo(uintT u){ union { uintT i; float f; } v; v.i = u << 16; return v.f; }
__device__ __forceinline__ float bhi(uintT u){ union { uintT i; float f; } v; v.i = u & 0xffff0000u; return v.f; }
__device__ __forceinline__ ushortT f2b(float f){
  __hip_bfloat16 h = __float2bfloat16(f);
  union { __hip_bfloat16 b; ushortT s; } v; v.b = h; return v.s;
}
__device__ __forceinline__ uintT packbf(float lo, float hi){
  return (uintT)f2b(lo) | ((uintT)f2b(hi) << 16);
}
__device__ __forceinline__ ushortT f2h(float f){
  __half h = __float2half(f);
  union { __half h; ushortT s; } v; v.h = h; return v.s;
}
__device__ __forceinline__ float h2f(ushortT s){
  union { __half h; ushortT s; } v; v.s = s; return __half2float(v.h);
}
__device__ __forceinline__ uintT packh(float lo, float hi){
  return (uintT)f2h(lo) | ((uintT)f2h(hi) << 16);
}
__device__ __forceinline__ float sigf(float x){ return 1.f/(1.f + __expf(-x)); }
__device__ __forceinline__ float tanh_f(float x){ float e = __expf(2.f*x); return 1.f - 2.f/(e+1.f); }

// ---------------- init: zero states (81920 f32) + barrier slots (128 ints) ----------------
__global__ __launch_bounds__(256) void k_init(float* __restrict__ p){
  int i = blockIdx.x*256 + threadIdx.x;
  if (i < 82048) p[i] = 0.f;
}

// ---------------- conv-weight transpose: Wf[a][c][i] -> wtc[cp][i][a] (bf16 pair c=2cp,2cp+1) ----------------
__global__ __launch_bounds__(256) void k_tconv(const float* __restrict__ Wf,
                                               uintT* __restrict__ wtc){
  int o = blockIdx.x*256 + threadIdx.x;       // 512*256*9 = 1,179,648
  int a  = o / 2304;
  int r  = o - a*2304;
  int cp = r / 9;
  int i  = r - cp*9;
  float v0 = Wf[(size_t)a*4608 + (size_t)(2*cp)*9 + i];
  float v1 = Wf[(size_t)a*4608 + (size_t)(2*cp)*9 + 9 + i];
  wtc[((size_t)cp*9 + i)*512 + a] = packbf(v0, v1);
}

// ---------------- gate-weight transpose: W[j][k] -> gwt[m][kp][j] (bf16 pair k=2kp,2kp+1) ----------------
// grid 512: m(4) x jt(32) x kt(4); LDS-tiled for coalescing both sides.
__global__ __launch_bounds__(256) void k_tgate(const float* __restrict__ w0,
    const float* __restrict__ w1, const float* __restrict__ w2,
    const float* __restrict__ w3, uintT* __restrict__ gwt){
  __shared__ uintT lds[64][65];
  int bid = blockIdx.x;
  int m  = bid & 3;
  int jt = (bid >> 2) & 31;
  int kt = bid >> 7;
  const float* W = (m==0) ? w0 : (m==1) ? w1 : (m==2) ? w2 : w3;
  int t = threadIdx.x, jl = t >> 2, q = t & 3;
  const float4* src = (const float4*)(W + (size_t)(jt*64 + jl)*512 + kt*128 + q*32);
  #pragma unroll
  for (int n=0;n<8;n++){
    float4 f = src[n];
    lds[jl][q*16 + 2*n]     = packbf(f.x, f.y);
    lds[jl][q*16 + 2*n + 1] = packbf(f.z, f.w);
  }
  __syncthreads();
  int kpl = t >> 2;
  #pragma unroll
  for (int n=0;n<4;n++){
    uint4 o4;
    o4.x = lds[q*16 + n*4 + 0][kpl];
    o4.y = lds[q*16 + n*4 + 1][kpl];
    o4.z = lds[q*16 + n*4 + 2][kpl];
    o4.w = lds[q*16 + n*4 + 3][kpl];
    *(uint4*)(gwt + ((size_t)(m*256 + kt*64 + kpl))*2048 + jt*64 + q*16 + n*4) = o4;
  }
}

// ---------------- conv 3x3 SAME -> fpj bf16 (b, p, a) ----------------
// grid 512: b(32) x y(8) x ah(2); 256 threads = a in half. Weights via wtc (coalesced).
__global__ __launch_bounds__(256) void k_conv(const float* __restrict__ feat,
                                              const uintT* __restrict__ wtc,
                                              const float* __restrict__ bfv,
                                              ushortT* __restrict__ fpj){
  int bid = blockIdx.x;
  int b  = bid >> 4;
  int y  = (bid >> 1) & 7;
  int ah = bid & 1;
  int a  = ah*256 + threadIdx.x;
  float acc[32];
  float bias = bfv[a];
  #pragma unroll
  for (int x=0;x<32;x++) acc[x]=bias;
  for (int cp=0; cp<256; cp++){
    uintT wq[9];
    #pragma unroll
    for (int i=0;i<9;i++) wq[i] = wtc[((size_t)cp*9 + i)*512 + a];   // coalesced
    #pragma unroll
    for (int cc=0; cc<2; cc++){
      int c = cp*2 + cc;
      float w[9];
      #pragma unroll
      for (int i=0;i<9;i++) w[i] = cc ? bhi(wq[i]) : blo(wq[i]);
      #pragma unroll
      for (int ky=0; ky<3; ky++){
        int yy = y + ky - 1;
        if (yy < 0 || yy > 7) continue;          // uniform per block
        const float4* irow = (const float4*)(feat + (((size_t)b*512 + c)*8 + yy)*32);
        float in[32];
        #pragma unroll
        for (int i2=0;i2<8;i2++){
          float4 qv = irow[i2];
          in[4*i2]=qv.x; in[4*i2+1]=qv.y; in[4*i2+2]=qv.z; in[4*i2+3]=qv.w;
        }
        float w0=w[ky*3+0], w1=w[ky*3+1], w2=w[ky*3+2];
        #pragma unroll
        for (int x=0;x<32;x++){
          float s = w1*in[x];
          if (x>0)  s += w0*in[x-1];
          if (x<31) s += w2*in[x+1];
          acc[x] += s;
        }
      }
    }
  }
  #pragma unroll
  for (int x=0;x<32;x++)
    fpj[((size_t)b*HWP + (size_t)(y*32+x))*512 + a] = f2b(acc[x]);
}

// ---------------- grid barrier: monotonic counter per slot ----------------
__device__ __forceinline__ void gridbar(int* __restrict__ bar, int slot){
  __syncthreads();
  if (threadIdx.x == 0){
    __threadfence();
    atomicAdd(&bar[slot], 1);
    while (atomicAdd(&bar[slot], 0) < NB) __builtin_amdgcn_s_sleep(2);
    __threadfence();
  }
  __syncthreads();
}

// ---------------- gate GEMM slice: this block's 64-k slice, 256-j slice, all 32 b ----------------
// thread: bq = tid&3 (8 b's), jt = tid>>2 (2 j's). Writes fp16 pairs to gpc[b*2048 + j].
__device__ __forceinline__ void gemm_nb128(const uintT* __restrict__ wkj0,  // gwt row base + j0
                                           ushortT* __restrict__ gpc,
                                           const float* __restrict__ xh,
                                           int j0, int bq){
  float acc0[8], acc1[8];
  #pragma unroll
  for (int r=0;r<8;r++){ acc0[r]=0.f; acc1[r]=0.f; }
  const float* xb = xh + bq*8*64;
  #pragma unroll 8
  for (int kpl=0; kpl<32; kpl++){
    uint2 wv = *(const uint2*)(wkj0 + (size_t)kpl*2048);
    float w00=blo(wv.x), w01=bhi(wv.x), w10=blo(wv.y), w11=bhi(wv.y);
    const float* xp = xb + kpl*2;
    #pragma unroll
    for (int r=0;r<8;r++){
      float2 xv = *(const float2*)(xp + r*64);
      acc0[r] += w00*xv.x + w01*xv.y;
      acc1[r] += w10*xv.x + w11*xv.y;
    }
  }
  #pragma unroll
  for (int r=0;r<8;r++){
    int b = bq*8 + r;
    *(uintT*)(gpc + (size_t)b*2048 + j0) = packh(acc0[r], acc1[r]);
  }
}

// ---------------- persistent 31-step kernel ----------------
__global__ __launch_bounds__(512) void k_steps(
    const int* __restrict__ gt, const float* __restrict__ Wemb,
    const uintT* __restrict__ gwt,
    const float* __restrict__ bih0, const float* __restrict__ bhh0,
    const float* __restrict__ bih1, const float* __restrict__ bhh1,
    const float* __restrict__ feat, const ushortT* __restrict__ fpj,
    const float* __restrict__ Wst, const float* __restrict__ watt,
    const float* __restrict__ Wout, const float* __restrict__ bout,
    float* __restrict__ st, ushortT* __restrict__ gp0, ushortT* __restrict__ gp1,
    int* __restrict__ bar, float* __restrict__ out)
{
  float* h0  = st;
  float* c0a = st + 16384;
  float* c0b = st + 32768;
  float* h1  = st + 49152;
  float* c1  = st + 65536;

  const int tid = threadIdx.x, bid = blockIdx.x;
  const int kc = bid & 15, jg = bid >> 4;      // kc: 64-k slice; jg: 256-j slice
  const int bq = tid & 3, jt = tid >> 2;
  const int j0 = jg*256 + jt*2;

  __shared__ __align__(16) float xh[2048];
  __shared__ __align__(16) float h1s[512];
  __shared__ __align__(16) float sps[512];
  __shared__ __align__(16) float watts[512];
  __shared__ __align__(16) float pals[512];
  __shared__ __align__(16) float attw[256];
  __shared__ __align__(16) float glim[512];
  __shared__ float red[4];

  const int kloc = (kc & 7) * 32;              // k-pair base within matrix
  const uintT* wgA = gwt + ((size_t)(((kc<8)?0:1)*256 + kloc))*2048 + j0;  // wih0/whh0
  const uintT* wgB = gwt + ((size_t)(((kc<8)?2:3)*256 + kloc))*2048 + j0;  // wih1/whh1

  int bs = 0;
  for (int t=0; t<STEPS; t++){
    // ---------- phase A: gates0 (input = [embed|h0_prev]) ----------
    if (kc < 8){
      for (int idx=tid; idx<2048; idx+=512){
        int b = idx>>6, kk = idx&63;
        float v = 0.f;
        if (t > 0){
          int g = gt[b*STEPS + t-1];
          v = Wemb[(size_t)(kc*64+kk)*V1 + g];
        }
        xh[idx] = v;
      }
    } else {
      for (int idx=tid; idx<2048; idx+=512){
        int b = idx>>6, kk = idx&63;
        xh[idx] = h0[b*RNN + (kc-8)*64 + kk];
      }
    }
    __syncthreads();
    gemm_nb128(wgA, gp0 + (size_t)kc*65536, xh, j0, bq);
    gridbar(bar, bs++);

    // ---------- phase B: cell0 recompute (kc<8) / h1 stage (kc>=8), then gates1 ----------
    if (kc < 8){
      const float* c0r = (t&1) ? c0b : c0a;
      float*       c0w = (t&1) ? c0a : c0b;
      for (int idx=tid; idx<2048; idx+=512){
        int b = idx>>6, kk = idx&63;
        int u = kc*64 + kk;
        float gi = bih0[u]        + bhh0[u];
        float gf = bih0[512+u]    + bhh0[512+u];
        float gg = bih0[1024+u]   + bhh0[1024+u];
        float go = bih0[1536+u]   + bhh0[1536+u];
        #pragma unroll
        for (int k2=0;k2<16;k2++){
          const ushortT* base = gp0 + (size_t)k2*65536 + (size_t)b*2048;
          gi += h2f(base[u]);      gf += h2f(base[512+u]);
          gg += h2f(base[1024+u]); go += h2f(base[1536+u]);
        }
        float ii=sigf(gi), ff=sigf(gf), g=tanh_f(gg), o=sigf(go);
        float cn = ff*c0r[b*RNN+u] + ii*g;
        float hn = o * tanh_f(cn);
        if (jg == 0){ c0w[b*RNN+u] = cn; h0[b*RNN+u] = hn; }
        xh[idx] = hn;
      }
    } else {
      for (int idx=tid; idx<2048; idx+=512){
        int b = idx>>6, kk = idx&63;
        xh[idx] = h1[b*RNN + (kc-8)*64 + kk];
      }
    }
    __syncthreads();
    gemm_nb128(wgB, gp1 + (size_t)kc*65536, xh, j0, bq);
    gridbar(bar, bs++);

    // ---------- phase C: cell1 + attention + logits (blocks 0..31) ----------
    if (bid < 32){
      const int b = bid;
      {
        int u = tid;
        float gi = bih1[u]        + bhh1[u];
        float gf = bih1[512+u]    + bhh1[512+u];
        float gg = bih1[1024+u]   + bhh1[1024+u];
        float go = bih1[1536+u]   + bhh1[1536+u];
        #pragma unroll
        for (int k2=0;k2<16;k2++){
          const ushortT* base = gp1 + (size_t)k2*65536 + (size_t)b*2048;
          gi += h2f(base[u]);      gf += h2f(base[512+u]);
          gg += h2f(base[1024+u]); go += h2f(base[1536+u]);
        }
        float ii=sigf(gi), ff=sigf(gf), g=tanh_f(gg), o=sigf(go);
        float cn = ff*c1[b*RNN+u] + ii*g;
        float hn = o * tanh_f(cn);
        c1[b*RNN+u] = cn; h1[b*RNN+u] = hn;
        h1s[u] = hn; watts[u] = watt[u];
      }
      __syncthreads();
      // sp = h1 @ W_state^T
      {
        const float4* wr = (const float4*)(Wst + (size_t)tid*512);
        float acc = 0.f;
        #pragma unroll 8
        for (int kb=0;kb<128;kb++){
          float4 q = wr[kb];
          const float* hx = h1s + kb*4;
          acc += q.x*hx[0] + q.y*hx[1] + q.z*hx[2] + q.w*hx[3];
        }
        sps[tid] = acc;
      }
      __syncthreads();
      // attention logits
      {
        int p = tid & 255, ac = tid >> 8;
        const uint4* fr = (const uint4*)(fpj + ((size_t)b*HWP + p)*512 + ac*256);
        float al = 0.f;
        #pragma unroll 8
        for (int kb=0;kb<32;kb++){
          uint4 q = fr[kb];
          float v[8] = {blo(q.x),bhi(q.x),blo(q.y),bhi(q.y),blo(q.z),bhi(q.z),blo(q.w),bhi(q.w)};
          int a0 = ac*256 + kb*8;
          #pragma unroll
          for (int i=0;i<8;i++)
            al += watts[a0+i] * tanh_f(v[i] + sps[a0+i]);
        }
        pals[tid] = al;
      }
      __syncthreads();
      // softmax over 256 positions
      {
        float al = (tid < 256) ? (pals[tid] + pals[256+tid]) : -1e30f;
        float m = al;
        #pragma unroll
        for (int off=32; off>0; off>>=1) m = fmaxf(m, __shfl_xor(m, off));
        if (tid < 256 && (tid & 63)==0) red[tid>>6] = m;
        __syncthreads();
        m = fmaxf(fmaxf(red[0],red[1]), fmaxf(red[2],red[3]));
        float e = (tid < 256) ? __expf(al - m) : 0.f;
        float s = e;
        #pragma unroll
        for (int off=32; off>0; off>>=1) s += __shfl_xor(s, off);
        __syncthreads();
        if (tid < 256 && (tid & 63)==0) red[tid>>6] = s;
        __syncthreads();
        if (tid < 256){
          float sa = red[0]+red[1]+red[2]+red[3];
          attw[tid] = e / sa;
        }
      }
      __syncthreads();
      // glimpse
      {
        const float4* fr = (const float4*)(feat + ((size_t)b*512 + tid)*HWP);
        float acc = 0.f;
        #pragma unroll 8
        for (int kb=0;kb<64;kb++){
          float4 q = fr[kb];
          const float* aw = attw + kb*4;
          acc += q.x*aw[0] + q.y*aw[1] + q.z*aw[2] + q.w*aw[3];
        }
        glim[tid] = acc;
      }
      __syncthreads();
      // logits
      if (tid < V1){
        const float4* wr = (const float4*)(Wout + (size_t)tid*1024);
        float acc = bout[tid];
        #pragma unroll 8
        for (int kb=0;kb<128;kb++){
          float4 q = wr[kb];
          const float* hx = h1s + kb*4;
          acc += q.x*hx[0] + q.y*hx[1] + q.z*hx[2] + q.w*hx[3];
        }
        #pragma unroll 8
        for (int kb=0;kb<128;kb++){
          float4 q = wr[128+kb];
          const float* gx = glim + kb*4;
          acc += q.x*gx[0] + q.y*gx[1] + q.z*gx[2] + q.w*gx[3];
        }
        out[(size_t)b*STEPS*V1 + (size_t)t*V1 + tid] = acc;
      }
    }
    gridbar(bar, bs++);
  }
}

extern "C" void kernel_launch(void* const* d_in, const int* in_sizes, int n_in,
                              void* d_out, int out_size, void* d_ws, size_t ws_size,
                              hipStream_t stream)
{
  const float* features = (const float*)d_in[0];
  const int*   gt       = (const int*)d_in[2];
  const float* Wf    = (const float*)d_in[3];
  const float* bfv   = (const float*)d_in[4];
  const float* Wst   = (const float*)d_in[5];
  const float* watt  = (const float*)d_in[6];
  const float* Wemb  = (const float*)d_in[7];
  const float* wih0  = (const float*)d_in[8];
  const float* whh0  = (const float*)d_in[9];
  const float* bih0  = (const float*)d_in[10];
  const float* bhh0  = (const float*)d_in[11];
  const float* wih1  = (const float*)d_in[12];
  const float* whh1  = (const float*)d_in[13];
  const float* bih1  = (const float*)d_in[14];
  const float* bhh1  = (const float*)d_in[15];
  const float* Wout  = (const float*)d_in[16];
  const float* bout  = (const float*)d_in[17];
  float* out = (float*)d_out;

  // ---- workspace layout (bytes), total ~26.0 MB ----
  char* wsb = (char*)d_ws;
  ushortT* fpj = (ushortT*)(wsb + 0);            // bf16 (b,p,a): 8,388,608 B
  ushortT* gp0 = (ushortT*)(wsb + 8388608);      // fp16 [16][32][2048]: 2,097,152 B
  ushortT* gp1 = (ushortT*)(wsb + 10485760);     // 2,097,152 B
  uintT*   gwt = (uintT*)  (wsb + 12582912);     // [4][256][2048] uint: 8,388,608 B
  uintT*   wtc = (uintT*)  (wsb + 20971520);     // [256][9][512] uint: 4,718,592 B
  float*   st  = (float*)  (wsb + 25690112);     // 81,920 f32 states
  int*     bar = (int*)    (wsb + 26017792);     // 128 barrier slots

  k_init <<<321, 256, 0, stream>>>(st);          // zeros states + bar (contiguous)
  k_tconv<<<4608, 256, 0, stream>>>(Wf, wtc);
  k_tgate<<<512, 256, 0, stream>>>(wih0, whh0, wih1, whh1, gwt);
  k_conv <<<512, 256, 0, stream>>>(features, wtc, bfv, fpj);
  k_steps<<<NB, 512, 0, stream>>>(gt, Wemb, gwt, bih0, bhh0, bih1, bhh1,
                                  features, fpj, Wst, watt, Wout, bout,
                                  st, gp0, gp1, bar, out);
  (void)in_sizes; (void)n_in; (void)out_size; (void)ws_size;
}

// Round 5
// 4950.748 us; speedup vs baseline: 1.1966x; 1.1966x over previous
//
#include <hip/hip_runtime.h>
#include <hip/hip_bf16.h>

// SARDecoder: 31-step teacher-forced attention LSTM decoder. fp32 in/out.
// Round 5: persistent step kernel, 1 hierarchical grid barrier/step, full-K
// j-sliced gate GEMMs (fp32 weights), M0 = wih0@Wemb precomputed, decoupled
// attention blocks. B=32, RNN=ATT=FEAT=512, V1=111, H=8, W=32, STEPS=31.

#define RNN   512
#define V1    111
#define STEPS 31
#define HWP   256
#define NBM   128    // main GEMM blocks
#define NATT  32     // attention blocks
#define XS_F  9216   // 256 * 36 (half-K stage, padded)
#define POOLF 9760   // XS_F + 544 (gsum)

typedef unsigned short ushortT;
typedef unsigned int   uintT;

__device__ __forceinline__ float blo(uintT u){ union { uintT i; float f; } v; v.i = u << 16; return v.f; }
__device__ __forceinline__ float bhi(uintT u){ union { uintT i; float f; } v; v.i = u & 0xffff0000u; return v.f; }
__device__ __forceinline__ ushortT f2b(float f){
  __hip_bfloat16 h = __float2bfloat16(f);
  union { __hip_bfloat16 b; ushortT s; } v; v.b = h; return v.s;
}
__device__ __forceinline__ uintT packbf(float lo, float hi){
  return (uintT)f2b(lo) | ((uintT)f2b(hi) << 16);
}
__device__ __forceinline__ float sigf(float x){ return 1.f/(1.f + __expf(-x)); }
__device__ __forceinline__ float tanh_f(float x){ float e = __expf(2.f*x); return 1.f - 2.f/(e+1.f); }

// ---------------- init: zero states (98304 f32) + barrier/attc slots (512 ints) ----------------
__global__ __launch_bounds__(256) void k_init(float* __restrict__ p){
  p[blockIdx.x*256 + threadIdx.x] = 0.f;   // grid 386 * 256 = 98816 exact
}

// ---------------- M0[j][g] = sum_k wih0[j][k] * Wemb[k][g]  (2048 x 111, pad 112) ----------------
__global__ __launch_bounds__(128) void k_m0(const float* __restrict__ wih0,
                                            const float* __restrict__ Wemb,
                                            float* __restrict__ M0){
  int j = blockIdx.x, g = threadIdx.x;
  if (g < V1){
    float acc = 0.f;
    const float* wr = wih0 + (size_t)j*512;
    for (int k=0;k<512;k++) acc += wr[k] * Wemb[(size_t)k*V1 + g];
    M0[(size_t)j*112 + g] = acc;
  }
}

// ---------------- conv-weight transpose: Wf[a][c][i] -> wtc[cp][i][a] (bf16 pair) ----------------
__global__ __launch_bounds__(256) void k_tconv(const float* __restrict__ Wf,
                                               uintT* __restrict__ wtc){
  int o = blockIdx.x*256 + threadIdx.x;       // 512*256*9 = 1,179,648
  int a  = o / 2304;
  int r  = o - a*2304;
  int cp = r / 9;
  int i  = r - cp*9;
  float v0 = Wf[(size_t)a*4608 + (size_t)(2*cp)*9 + i];
  float v1 = Wf[(size_t)a*4608 + (size_t)(2*cp)*9 + 9 + i];
  wtc[((size_t)cp*9 + i)*512 + a] = packbf(v0, v1);
}

// ---------------- conv 3x3 SAME -> fpj bf16 (b, p, a) ----------------
__global__ __launch_bounds__(256) void k_conv(const float* __restrict__ feat,
                                              const uintT* __restrict__ wtc,
                                              const float* __restrict__ bfv,
                                              ushortT* __restrict__ fpj){
  int bid = blockIdx.x;
  int b  = bid >> 4;
  int y  = (bid >> 1) & 7;
  int ah = bid & 1;
  int a  = ah*256 + threadIdx.x;
  float acc[32];
  float bias = bfv[a];
  #pragma unroll
  for (int x=0;x<32;x++) acc[x]=bias;
  for (int cp=0; cp<256; cp++){
    uintT wq[9];
    #pragma unroll
    for (int i=0;i<9;i++) wq[i] = wtc[((size_t)cp*9 + i)*512 + a];   // coalesced
    #pragma unroll
    for (int cc=0; cc<2; cc++){
      int c = cp*2 + cc;
      float w[9];
      #pragma unroll
      for (int i=0;i<9;i++) w[i] = cc ? bhi(wq[i]) : blo(wq[i]);
      #pragma unroll
      for (int ky=0; ky<3; ky++){
        int yy = y + ky - 1;
        if (yy < 0 || yy > 7) continue;          // uniform per block
        const float4* irow = (const float4*)(feat + (((size_t)b*512 + c)*8 + yy)*32);
        float in[32];
        #pragma unroll
        for (int i2=0;i2<8;i2++){
          float4 qv = irow[i2];
          in[4*i2]=qv.x; in[4*i2+1]=qv.y; in[4*i2+2]=qv.z; in[4*i2+3]=qv.w;
        }
        float w0=w[ky*3+0], w1=w[ky*3+1], w2=w[ky*3+2];
        #pragma unroll
        for (int x=0;x<32;x++){
          float s = w1*in[x];
          if (x>0)  s += w0*in[x-1];
          if (x<31) s += w2*in[x+1];
          acc[x] += s;
        }
      }
    }
  }
  #pragma unroll
  for (int x=0;x<32;x++)
    fpj[((size_t)b*HWP + (size_t)(y*32+x))*512 + a] = f2b(acc[x]);
}

// ---------------- hierarchical grid barrier (main blocks only) ----------------
// bar[0]=root; bar[16 + g*16]=leaf g (16 groups of 8); monotonic counters.
__device__ __forceinline__ void mbar(int* __restrict__ bar, int bid, int round, bool wait){
  __syncthreads();
  if (threadIdx.x == 0){
    __threadfence();
    int* leaf = bar + 16 + (bid >> 3)*16;
    int old = __hip_atomic_fetch_add(leaf, 1, __ATOMIC_ACQ_REL, __HIP_MEMORY_SCOPE_AGENT);
    if (old == round*8 + 7)
      __hip_atomic_fetch_add(bar, 1, __ATOMIC_ACQ_REL, __HIP_MEMORY_SCOPE_AGENT);
    if (wait){
      int target = 16*(round+1);
      while (__hip_atomic_load(bar, __ATOMIC_RELAXED, __HIP_MEMORY_SCOPE_AGENT) < target)
        __builtin_amdgcn_s_sleep(1);
      __threadfence();
    }
  }
  __syncthreads();
}

// ---------------- stage half-K (256 rows x 32 b) of a [512][32] state into xs[k][36] ----------------
__device__ __forceinline__ void stage_half(float* __restrict__ xs,
                                           const float* __restrict__ srcT,
                                           int half, int tid){
  const float* s = srcT + half*8192;
  #pragma unroll
  for (int i=0;i<16;i++){
    int idx = tid + i*512;
    xs[(idx >> 5)*36 + (idx & 31)] = s[idx];
  }
}

// ---------------- GEMM quarter: acc[4j][4b] += W[rows jq*512+u0..+3][koff+kq*16 .. +16) . xs ----------------
__device__ __forceinline__ void gemm_half(float acc[4][4], const float* __restrict__ W,
                                          const float* __restrict__ xs,
                                          int koff, int kq, int jq, int bq, int u0){
  const float* w0 = W + ((size_t)(jq*512 + u0))*512 + koff + kq*16;
  const float* xp = xs + (kq*16)*36 + bq*4;
  #pragma unroll
  for (int kk=0; kk<16; kk+=4){
    float4 xv0 = *(const float4*)(xp + (kk+0)*36);
    float4 xv1 = *(const float4*)(xp + (kk+1)*36);
    float4 xv2 = *(const float4*)(xp + (kk+2)*36);
    float4 xv3 = *(const float4*)(xp + (kk+3)*36);
    #pragma unroll
    for (int r=0;r<4;r++){
      float4 wv = *(const float4*)(w0 + (size_t)r*512 + kk);
      acc[r][0] += wv.x*xv0.x + wv.y*xv1.x + wv.z*xv2.x + wv.w*xv3.x;
      acc[r][1] += wv.x*xv0.y + wv.y*xv1.y + wv.z*xv2.y + wv.w*xv3.y;
      acc[r][2] += wv.x*xv0.z + wv.y*xv1.z + wv.z*xv2.z + wv.w*xv3.z;
      acc[r][3] += wv.x*xv0.w + wv.y*xv1.w + wv.z*xv2.w + wv.w*xv3.w;
    }
  }
}

// ---------------- persistent 31-step kernel: 128 GEMM blocks + 32 attention blocks ----------------
__global__ __launch_bounds__(512) void k_steps(
    const int* __restrict__ gt, const float* __restrict__ M0,
    const float* __restrict__ whh0,
    const float* __restrict__ wih1, const float* __restrict__ whh1,
    const float* __restrict__ bih0, const float* __restrict__ bhh0,
    const float* __restrict__ bih1, const float* __restrict__ bhh1,
    const float* __restrict__ feat, const ushortT* __restrict__ fpj,
    const float* __restrict__ Wst, const float* __restrict__ watt,
    const float* __restrict__ Wout, const float* __restrict__ bout,
    float* __restrict__ st, int* __restrict__ bar, float* __restrict__ out)
{
  __shared__ __align__(16) float pool[POOLF];
  const int tid = threadIdx.x, bid = blockIdx.x;
  float* h0T0 = st;             // [u][b] parity 0
  float* h0T1 = st + 16384;
  float* h1T0 = st + 32768;
  float* h1T1 = st + 49152;
  float* c0T  = st + 65536;
  float* c1T  = st + 81920;
  int* attc = bar + 300;

  if (bid < NBM){
    // ================= main GEMM block =================
    float* xs   = pool;            // also reused as part[] after GEMM
    float* part = pool;            // [kq*16+jj][33] overlay (8448 <= 9216)
    float* gsum = pool + XS_F;     // [jj][33]
    const int kq = tid >> 5, jq = (tid >> 3) & 3, bq = tid & 7;
    const int u0 = bid*4;

    for (int t=0; t<STEPS; t++){
      const float* h0r = (t & 1) ? h0T0 : h0T1;   // prev parity
      float*       h0w = (t & 1) ? h0T1 : h0T0;   // cur parity
      const float* h1r = (t & 1) ? h1T0 : h1T1;
      float*       h1w = (t & 1) ? h1T1 : h1T0;

      // ---------- phase 1: gates0 = M0 col + h0_prev @ whh0^T ; cell0 ----------
      float acc[4][4] = {{0.f}};
      stage_half(xs, h0r, 0, tid); __syncthreads();
      gemm_half(acc, whh0, xs, 0,   kq, jq, bq, u0); __syncthreads();
      stage_half(xs, h0r, 1, tid); __syncthreads();
      gemm_half(acc, whh0, xs, 256, kq, jq, bq, u0); __syncthreads();
      #pragma unroll
      for (int r=0;r<4;r++)
        #pragma unroll
        for (int bb=0;bb<4;bb++)
          part[(kq*16 + jq*4 + r)*33 + bq*4 + bb] = acc[r][bb];
      __syncthreads();
      {
        int jj = tid >> 5, b = tid & 31;
        float s = 0.f;
        #pragma unroll
        for (int k2=0;k2<16;k2++) s += part[(k2*16 + jj)*33 + b];
        int m = jj >> 2, ul = jj & 3;
        int j = m*512 + u0 + ul;
        s += bih0[j] + bhh0[j];
        if (t > 0) s += M0[(size_t)j*112 + gt[b*STEPS + t - 1]];
        gsum[jj*33 + b] = s;
      }
      __syncthreads();
      if (tid < 128){
        int ul = tid >> 5, b = tid & 31;
        float gi = gsum[(0*4+ul)*33 + b];
        float gf = gsum[(1*4+ul)*33 + b];
        float gg = gsum[(2*4+ul)*33 + b];
        float go = gsum[(3*4+ul)*33 + b];
        int idx = (u0+ul)*32 + b;
        float cn = sigf(gf)*c0T[idx] + sigf(gi)*tanh_f(gg);
        c0T[idx] = cn;
        h0w[idx] = sigf(go)*tanh_f(cn);
      }
      mbar(bar, bid, t, true);

      // ---------- phase 2: gates1 = h0_cur @ wih1^T + h1_prev @ whh1^T ; cell1 ----------
      #pragma unroll
      for (int r=0;r<4;r++){ acc[r][0]=0.f; acc[r][1]=0.f; acc[r][2]=0.f; acc[r][3]=0.f; }
      stage_half(xs, h0w, 0, tid); __syncthreads();
      gemm_half(acc, wih1, xs, 0,   kq, jq, bq, u0); __syncthreads();
      stage_half(xs, h0w, 1, tid); __syncthreads();
      gemm_half(acc, wih1, xs, 256, kq, jq, bq, u0); __syncthreads();
      stage_half(xs, h1r, 0, tid); __syncthreads();
      gemm_half(acc, whh1, xs, 0,   kq, jq, bq, u0); __syncthreads();
      stage_half(xs, h1r, 1, tid); __syncthreads();
      gemm_half(acc, whh1, xs, 256, kq, jq, bq, u0); __syncthreads();
      #pragma unroll
      for (int r=0;r<4;r++)
        #pragma unroll
        for (int bb=0;bb<4;bb++)
          part[(kq*16 + jq*4 + r)*33 + bq*4 + bb] = acc[r][bb];
      // back-pressure: att(t-2) must be done before overwriting its h1 parity
      if (tid == 0 && t >= 2){
        while (__hip_atomic_load(attc, __ATOMIC_RELAXED, __HIP_MEMORY_SCOPE_AGENT) < 32*(t-1))
          __builtin_amdgcn_s_sleep(2);
      }
      __syncthreads();
      {
        int jj = tid >> 5, b = tid & 31;
        float s = 0.f;
        #pragma unroll
        for (int k2=0;k2<16;k2++) s += part[(k2*16 + jj)*33 + b];
        int m = jj >> 2, ul = jj & 3;
        int j = m*512 + u0 + ul;
        s += bih1[j] + bhh1[j];
        gsum[jj*33 + b] = s;
      }
      __syncthreads();
      if (tid < 128){
        int ul = tid >> 5, b = tid & 31;
        float gi = gsum[(0*4+ul)*33 + b];
        float gf = gsum[(1*4+ul)*33 + b];
        float gg = gsum[(2*4+ul)*33 + b];
        float go = gsum[(3*4+ul)*33 + b];
        int idx = (u0+ul)*32 + b;
        float cn = sigf(gf)*c1T[idx] + sigf(gi)*tanh_f(gg);
        c1T[idx] = cn;
        h1w[idx] = sigf(go)*tanh_f(cn);
      }
    }
    mbar(bar, bid, STEPS, false);   // final arrival (signals ph2(30) complete)
  } else {
    // ================= attention block (one batch item) =================
    const int b = bid - NBM;
    float* h1s   = pool;
    float* sps   = pool + 512;
    float* watts = pool + 1024;
    float* pals  = pool + 1536;
    float* attw  = pool + 2048;
    float* glim  = pool + 2304;
    float* red   = pool + 2816;
    watts[tid] = watt[tid];

    for (int t=0; t<STEPS; t++){
      if (tid == 0){
        int target = 16*(t+2);    // all ph2(t) done == barrier round t+1 fully arrived
        while (__hip_atomic_load(bar, __ATOMIC_RELAXED, __HIP_MEMORY_SCOPE_AGENT) < target)
          __builtin_amdgcn_s_sleep(4);
        __threadfence();
      }
      __syncthreads();
      const float* h1c = (t & 1) ? h1T1 : h1T0;
      h1s[tid] = h1c[tid*32 + b];
      __syncthreads();
      // sp = h1 @ W_state^T
      {
        const float4* wr = (const float4*)(Wst + (size_t)tid*512);
        float acc = 0.f;
        #pragma unroll 8
        for (int kb=0;kb<128;kb++){
          float4 q = wr[kb];
          const float* hx = h1s + kb*4;
          acc += q.x*hx[0] + q.y*hx[1] + q.z*hx[2] + q.w*hx[3];
        }
        sps[tid] = acc;
      }
      __syncthreads();
      // attention logits over (p, a-half)
      {
        int p = tid & 255, ac = tid >> 8;
        const uint4* fr = (const uint4*)(fpj + ((size_t)b*HWP + p)*512 + ac*256);
        float al = 0.f;
        #pragma unroll 8
        for (int kb=0;kb<32;kb++){
          uint4 q = fr[kb];
          float v[8] = {blo(q.x),bhi(q.x),blo(q.y),bhi(q.y),blo(q.z),bhi(q.z),blo(q.w),bhi(q.w)};
          int a0 = ac*256 + kb*8;
          #pragma unroll
          for (int i=0;i<8;i++)
            al += watts[a0+i] * tanh_f(v[i] + sps[a0+i]);
        }
        pals[tid] = al;
      }
      __syncthreads();
      // softmax over 256 positions
      {
        float al = (tid < 256) ? (pals[tid] + pals[256+tid]) : -1e30f;
        float m = al;
        #pragma unroll
        for (int off=32; off>0; off>>=1) m = fmaxf(m, __shfl_xor(m, off));
        if (tid < 256 && (tid & 63)==0) red[tid>>6] = m;
        __syncthreads();
        m = fmaxf(fmaxf(red[0],red[1]), fmaxf(red[2],red[3]));
        float e = (tid < 256) ? __expf(al - m) : 0.f;
        float s = e;
        #pragma unroll
        for (int off=32; off>0; off>>=1) s += __shfl_xor(s, off);
        __syncthreads();
        if (tid < 256 && (tid & 63)==0) red[tid>>6] = s;
        __syncthreads();
        if (tid < 256){
          float sa = red[0]+red[1]+red[2]+red[3];
          attw[tid] = e / sa;
        }
      }
      __syncthreads();
      // glimpse[c] = sum_p feat[b,c,p] * attw[p]
      {
        const float4* fr = (const float4*)(feat + ((size_t)b*512 + tid)*HWP);
        float acc = 0.f;
        #pragma unroll 8
        for (int kb=0;kb<64;kb++){
          float4 q = fr[kb];
          const float* aw = attw + kb*4;
          acc += q.x*aw[0] + q.y*aw[1] + q.z*aw[2] + q.w*aw[3];
        }
        glim[tid] = acc;
      }
      __syncthreads();
      // logits = [h1, glimpse] @ W_out^T + b_out
      if (tid < V1){
        const float4* wr = (const float4*)(Wout + (size_t)tid*1024);
        float acc = bout[tid];
        #pragma unroll 8
        for (int kb=0;kb<128;kb++){
          float4 q = wr[kb];
          const float* hx = h1s + kb*4;
          acc += q.x*hx[0] + q.y*hx[1] + q.z*hx[2] + q.w*hx[3];
        }
        #pragma unroll 8
        for (int kb=0;kb<128;kb++){
          float4 q = wr[128+kb];
          const float* gx = glim + kb*4;
          acc += q.x*gx[0] + q.y*gx[1] + q.z*gx[2] + q.w*gx[3];
        }
        out[(size_t)b*STEPS*V1 + (size_t)t*V1 + tid] = acc;
      }
      __syncthreads();
      if (tid == 0){
        __threadfence();
        __hip_atomic_fetch_add(attc, 1, __ATOMIC_ACQ_REL, __HIP_MEMORY_SCOPE_AGENT);
      }
    }
  }
}

extern "C" void kernel_launch(void* const* d_in, const int* in_sizes, int n_in,
                              void* d_out, int out_size, void* d_ws, size_t ws_size,
                              hipStream_t stream)
{
  const float* features = (const float*)d_in[0];
  const int*   gt       = (const int*)d_in[2];
  const float* Wf    = (const float*)d_in[3];
  const float* bfv   = (const float*)d_in[4];
  const float* Wst   = (const float*)d_in[5];
  const float* watt  = (const float*)d_in[6];
  const float* Wemb  = (const float*)d_in[7];
  const float* wih0  = (const float*)d_in[8];
  const float* whh0  = (const float*)d_in[9];
  const float* bih0  = (const float*)d_in[10];
  const float* bhh0  = (const float*)d_in[11];
  const float* wih1  = (const float*)d_in[12];
  const float* whh1  = (const float*)d_in[13];
  const float* bih1  = (const float*)d_in[14];
  const float* bhh1  = (const float*)d_in[15];
  const float* Wout  = (const float*)d_in[16];
  const float* bout  = (const float*)d_in[17];
  float* out = (float*)d_out;

  // ---- workspace layout (bytes), total ~14.42 MB ----
  char* wsb = (char*)d_ws;
  ushortT* fpj = (ushortT*)(wsb + 0);            // bf16 (b,p,a): 8,388,608 B
  uintT*   wtc = (uintT*)  (wsb + 8388608);      // [256][9][512] uint: 4,718,592 B
  float*   M0  = (float*)  (wsb + 13107200);     // [2048][112] f32: 917,504 B
  float*   st  = (float*)  (wsb + 14024704);     // 98,304 f32 states: 393,216 B
  int*     bar = (int*)    (wsb + 14417920);     // 512 ints (root/leaves/attc)

  k_init <<<386, 256, 0, stream>>>(st);          // zeros st + bar (contiguous)
  k_tconv<<<4608, 256, 0, stream>>>(Wf, wtc);
  k_m0   <<<2048, 128, 0, stream>>>(wih0, Wemb, M0);
  k_conv <<<512, 256, 0, stream>>>(features, wtc, bfv, fpj);
  k_steps<<<NBM + NATT, 512, 0, stream>>>(gt, M0, whh0, wih1, whh1,
                                          bih0, bhh0, bih1, bhh1,
                                          features, fpj, Wst, watt, Wout, bout,
                                          st, bar, out);
  (void)in_sizes; (void)n_in; (void)out_size; (void)ws_size;
}